// Round 3
// baseline (162.860 us; speedup 1.0000x reference)
//
#include <hip/hip_runtime.h>

// Batched CBF-QP dual FISTA, 4 lanes per problem, PACKED fp32 (v_pk_fma_f32),
// TWO problems per thread (r12).
// r11 post-mortem: VALUBusy 74% at 2 waves/SIMD, instr cuts ~neutral ->
// latency-bound, not issue-bound. r12 halves thread count and gives each
// thread two independent problems (A at q, B at q+half). Every loop body
// (power iteration, FISTA) processes BOTH problems so the scheduler can
// interleave the two independent dependency chains -> one wave can saturate
// the SIMD (wave64 VALU = 1 op / 2 cyc = SIMD-32 throughput).
//
// Row partition per problem (25 active rows; all-zero "extra" row inert):
//   pair {0,1} owns slack col2: lane0 obs0..5; lane1 obs6..9, slack0, box_a-
//   pair {2,3} owns slack col3: lane2 nei0..5; lane3 nei6, slack1, box_a+, box_w-, box_w+, pad
//   col4 (conn + slack2) replicated in all 4 lanes, packed as one v2 row.
// Sustained-clock note: fp32-VALU-saturated kernels run at ~1.6 GHz on MI355X.

typedef float v2f __attribute__((ext_vector_type(2)));

namespace {
constexpr int N_POWER = 30;   // even
constexpr int N_FISTA = 300;  // divisible by 4
constexpr float PINV_S = 1.0f / 200.0f;  // 1/(2*W_SLACK)
constexpr float BIG = 1000.0f;

constexpr double csqrt(double x) {
    double r = x * 0.5 + 0.5;
    for (int i = 0; i < 50; ++i) r = 0.5 * (r + x / r);
    return r;
}
// beta stored pre-duplicated: {b0,b0,b1,b1,b2,b2,b3,b3} per oct; one scalar
// load per 4 iterations, prefetched one ahead, shared by both problems.
struct alignas(32) BOct { float b[8]; };
struct BetaTab8 { BOct q[N_FISTA / 4 + 1]; };  // +1 pad oct for prefetch
constexpr BetaTab8 make_beta8() {
    BetaTab8 t{};
    float tk = 1.0f;
    for (int k = 0; k < N_FISTA; ++k) {
        const float tk1 = 0.5f * (1.0f + (float)csqrt(1.0 + 4.0 * (double)tk * (double)tk));
        const float bb = (tk - 1.0f) / tk1;
        t.q[k / 4].b[(k % 4) * 2]     = bb;
        t.q[k / 4].b[(k % 4) * 2 + 1] = bb;
        tk = tk1;
    }
    return t;
}
}
__constant__ BetaTab8 BETA8 = make_beta8();

template <int CTRL>
__device__ __forceinline__ float dpp_xor_add(float x) {
    // CTRL: 0xB1 = quad_perm(1,0,3,2) = xor1 ; 0x4E = quad_perm(2,3,0,1) = xor2
    // mov_dpp + add: compiler handles DPP read-after-VALU hazards and fuses
    // via GCNDPPCombine (r10 lesson: raw asm v_add_f32_dpp skips hazard nops).
    int perm = __builtin_amdgcn_mov_dpp(__float_as_int(x), CTRL, 0xF, 0xF, true);
    return x + __int_as_float(perm);
}

__device__ __forceinline__ v2f vfma(v2f a, v2f b, v2f c) {
    return __builtin_elementwise_fma(a, b, c);
}
__device__ __forceinline__ v2f vmax0(v2f a) {
    const v2f z = {0.f, 0.f};
    return __builtin_elementwise_max(a, z);
}

// ---- per-problem constant state (rows) ----
struct Rows {
    v2f R0[3], R1[3], RA[3], NB[3];
    v2f C0v, C1v, CB2, NCBv;
    float c0, c1, cB;
    float u0, u1;
};

__device__ __forceinline__ void build_rows(
    int p, int sub,
    const float* __restrict__ u_nom, const float* __restrict__ v_cur,
    const float* __restrict__ p_obs, const float* __restrict__ obs_mask,
    const float* __restrict__ p_ag,  const float* __restrict__ v_ag,
    const float* __restrict__ ag_mask, const float* __restrict__ p_c,
    const float* __restrict__ v_c,   const float* __restrict__ c_mask,
    Rows& R)
{
    const float v = v_cur[p];
    R.u0 = u_nom[2 * p];
    R.u1 = u_nom[2 * p + 1];

    float r0[6], r1[6], rA[6], nb[6];
#pragma unroll
    for (int s = 0; s < 6; ++s) { r0[s] = 0.f; r1[s] = 0.f; rA[s] = 0.f; nb[s] = -BIG; }

    auto obs_row = [&](int i, int s) {
        const float lx = p_obs[(p * 10 + i) * 2];
        const float ly = p_obs[(p * 10 + i) * 2 + 1];
        const float m  = obs_mask[p * 10 + i];
        const float h   = lx * lx + ly * ly - 0.25f;            // D_OBS^2
        const float hd  = -2.f * lx * v;
        const float rhs = 2.f * v * v + 3.f * hd + 2.f * h;     // DAMP=3, STIFF=2
        r0[s] = 2.f * lx * m;
        r1[s] = 2.f * ly * v * m;
        rA[s] = -m;
        nb[s] = (m > 0.f) ? -rhs : -BIG;
    };
    auto nei_row = [&](int j, int s) {
        const float ax  = p_ag[(p * 7 + j) * 2];
        const float ay  = p_ag[(p * 7 + j) * 2 + 1];
        const float vjx = v_ag[(p * 7 + j) * 2];
        const float vjy = v_ag[(p * 7 + j) * 2 + 1];
        const float m   = ag_mask[p * 7 + j];
        const float h   = ax * ax + ay * ay - 0.64f;            // D_SAFE^2
        const float hd  = -2.f * ax * v + 2.f * (ax * vjx + ay * vjy);
        const float hdd = 2.f * v * v - 2.f * v * vjx
                        + 2.f * (-v * vjx + vjx * vjx + vjy * vjy);
        const float rhs = hdd + 3.f * hd + 2.f * h;             // DAMP_A=3, STIFF_A=2
        r0[s] = 2.f * ax * m;
        r1[s] = (2.f * ay * v - 2.f * ay * vjx + 2.f * ax * vjy) * m;
        rA[s] = -m;
        nb[s] = (m > 0.f) ? -rhs : -BIG;
    };

    if (sub == 0) {
        obs_row(0, 0); obs_row(1, 1); obs_row(2, 2);
        obs_row(3, 3); obs_row(4, 4); obs_row(5, 5);
    } else if (sub == 1) {
        obs_row(6, 0); obs_row(7, 1); obs_row(8, 2); obs_row(9, 3);
        rA[4] = -1.f; nb[4] = 0.f;     // slack0: -delta_obs <= 0 (col2)
        r0[5] = -1.f; nb[5] = -2.f;    // -a <= A_MAX
    } else if (sub == 2) {
        nei_row(0, 0); nei_row(1, 1); nei_row(2, 2);
        nei_row(3, 3); nei_row(4, 4); nei_row(5, 5);
    } else {
        nei_row(6, 0);
        rA[1] = -1.f; nb[1] = 0.f;     // slack1: -delta_agent <= 0 (col3)
        r0[2] =  1.f; nb[2] = -2.f;    //  a <= A_MAX
        r1[3] = -1.f; nb[3] = -1.f;    // -w <= W_MAX
        r1[4] =  1.f; nb[4] = -1.f;    //  w <= W_MAX
        // slot5 = pad (zero coeffs, nb=-BIG): lambda provably stays 0
    }

#pragma unroll
    for (int k = 0; k < 3; ++k) {
        R.R0[k] = v2f{r0[2 * k], r0[2 * k + 1]};
        R.R1[k] = v2f{r1[2 * k], r1[2 * k + 1]};
        R.RA[k] = v2f{rA[2 * k], rA[2 * k + 1]};
        R.NB[k] = v2f{nb[2 * k], nb[2 * k + 1]};
    }

    // conn + slack2 (col4), replicated in every lane, packed as one v2 row
    {
        const float cx  = p_c[2 * p];
        const float cy  = p_c[2 * p + 1];
        const float cvx = v_c[2 * p];
        const float cvy = v_c[2 * p + 1];
        const float m   = c_mask[p];
        const float h   = 25.f - (cx * cx + cy * cy);           // D_MAX^2
        const float hd  = 2.f * cx * v - 2.f * (cx * cvx + cy * cvy);
        const float hdd = -(2.f * v * v - 2.f * v * cvx
                          + 2.f * (-v * cvx + cvx * cvx + cvy * cvy));
        const float rhs = hdd + 3.f * hd + 2.f * h;             // DAMP_CN=3, STIFF_CN=2
        R.c0 = -2.f * cx * m;
        R.c1 = -(2.f * cy * v - 2.f * cy * cvx + 2.f * cx * cvy) * m;
        R.cB = -m;
        const float ncb = (m > 0.f) ? -rhs : -BIG;
        R.C0v  = v2f{R.c0, 0.f};
        R.C1v  = v2f{R.c1, 0.f};
        R.CB2  = v2f{R.cB, -1.f};
        R.NCBv = v2f{ncb, 0.f};
    }
}

// ---- power-iteration pieces (called A,B interleaved from one loop) ----
__device__ __forceinline__ void apply_M(const Rows& R, v2f (&PV)[3], float& pvC, float& pvS)
{
    v2f A0 = vfma(R.R0[0], PV[0], vfma(R.R0[1], PV[1], R.R0[2] * PV[2]));
    v2f A1 = vfma(R.R1[0], PV[0], vfma(R.R1[1], PV[1], R.R1[2] * PV[2]));
    v2f AA = vfma(R.RA[0], PV[0], vfma(R.RA[1], PV[1], R.RA[2] * PV[2]));
    float a0 = A0.x + A0.y, a1 = A1.x + A1.y, aA = AA.x + AA.y;
    a0 = dpp_xor_add<0xB1>(a0); a0 = dpp_xor_add<0x4E>(a0);
    a1 = dpp_xor_add<0xB1>(a1); a1 = dpp_xor_add<0x4E>(a1);
    aA = dpp_xor_add<0xB1>(aA);
    a0 = fmaf(R.c0, pvC, a0);
    a1 = fmaf(R.c1, pvC, a1);
    const float aC = fmaf(R.cB, pvC, -pvS);
    const float x0 = 0.5f * a0, x1 = 0.5f * a1;
    const float xA = PINV_S * aA, xC = PINV_S * aC;
    const v2f X0 = {x0, x0}, X1 = {x1, x1}, XA = {xA, xA};
#pragma unroll
    for (int k = 0; k < 3; ++k)
        PV[k] = vfma(R.R0[k], X0, vfma(R.R1[k], X1, R.RA[k] * XA));
    pvC = fmaf(R.c0, x0, fmaf(R.c1, x1, R.cB * xC));
    pvS = -xC;
}

__device__ __forceinline__ void pnorm(v2f (&PV)[3], float& pvC, float& pvS)
{
    v2f NS = vfma(PV[0], PV[0], vfma(PV[1], PV[1], PV[2] * PV[2]));
    float nsq = NS.x + NS.y;
    nsq = dpp_xor_add<0xB1>(nsq); nsq = dpp_xor_add<0x4E>(nsq);
    nsq = fmaf(pvC, pvC, fmaf(pvS, pvS, nsq));
    const float inv = __builtin_amdgcn_rsqf(nsq + 1e-24f);
    const v2f INV = {inv, inv};
#pragma unroll
    for (int k = 0; k < 3; ++k) PV[k] = PV[k] * INV;
    pvC *= inv;
    pvS *= inv;
}

__device__ __forceinline__ void step_consts(const Rows& R, const v2f (&PV)[3],
                                            float pvC, float pvS,
                                            float& nsh, float& pA)
{
    v2f A0 = vfma(R.R0[0], PV[0], vfma(R.R0[1], PV[1], R.R0[2] * PV[2]));
    v2f A1 = vfma(R.R1[0], PV[0], vfma(R.R1[1], PV[1], R.R1[2] * PV[2]));
    v2f AA = vfma(R.RA[0], PV[0], vfma(R.RA[1], PV[1], R.RA[2] * PV[2]));
    float a0 = A0.x + A0.y, a1 = A1.x + A1.y, aA = AA.x + AA.y;
    a0 = dpp_xor_add<0xB1>(a0); a0 = dpp_xor_add<0x4E>(a0);
    a1 = dpp_xor_add<0xB1>(a1); a1 = dpp_xor_add<0x4E>(a1);
    aA = dpp_xor_add<0xB1>(aA);
    a0 = fmaf(R.c0, pvC, a0);
    a1 = fmaf(R.c1, pvC, a1);
    const float aC = fmaf(R.cB, pvC, -pvS);
    // pair sums of slack cols: after xor1, lanes {0,1} hold col2, {2,3} col3
    float tq = aA * aA;
    tq = dpp_xor_add<0x4E>(tq);     // col2^2 + col3^2 in every lane
    const float L = 0.5f * (a0 * a0 + a1 * a1) + PINV_S * (tq + aC * aC);
    const float step = __builtin_amdgcn_rcpf(L + 1e-6f);
    nsh = -0.5f * step;
    pA  = -PINV_S * step;
}

// ---- FISTA half-step (z = y/step scale; pA pre-folded into RA2/CB2s) ----
__device__ __forceinline__ void half_step(const Rows& R, const v2f (&RA2)[3], v2f CB2s,
                                          float nsh,
                                          v2f (&ZV)[3], v2f& zCS,
                                          v2f (&ln)[3], const v2f (&lp)[3],
                                          v2f& lnCS, v2f lpCS, v2f Bv)
{
    v2f A0 = vfma(R.R0[0], ZV[0], vfma(R.R0[1], ZV[1], R.R0[2] * ZV[2]));
    v2f A1 = vfma(R.R1[0], ZV[0], vfma(R.R1[1], ZV[1], R.R1[2] * ZV[2]));
    v2f AA = vfma(RA2[0], ZV[0], vfma(RA2[1], ZV[1], RA2[2] * ZV[2]));
    float a0 = A0.x + A0.y, a1 = A1.x + A1.y, aA = AA.x + AA.y;
    a0 = dpp_xor_add<0xB1>(a0); a0 = dpp_xor_add<0x4E>(a0);
    a1 = dpp_xor_add<0xB1>(a1); a1 = dpp_xor_add<0x4E>(a1);
    aA = dpp_xor_add<0xB1>(aA);         // == xA (pA pre-folded)
    const v2f tCs = CB2s * zCS;         // {pA*cB*zC, -pA*zS}
    const float xC = tCs.x + tCs.y;     // == pA*(cB*zC - zS)
    const float x0 = fmaf(nsh, fmaf(R.c0, zCS.x, a0), R.u0);  // x = -(q + A^T y)*Pinv
    const float x1 = fmaf(nsh, fmaf(R.c1, zCS.x, a1), R.u1);
    const v2f X0 = {x0, x0}, X1 = {x1, x1}, XA = {aA, aA}, XC = {xC, xC};
#pragma unroll
    for (int k = 0; k < 3; ++k) {
        const v2f resid = vfma(R.R0[k], X0, vfma(R.R1[k], X1, vfma(R.RA[k], XA, R.NB[k])));
        const v2f l = vmax0(ZV[k] + resid);
        ZV[k] = vfma(Bv, l - lp[k], l);
        ln[k] = l;
    }
    {   // packed conn(.x) + slack2(.y)
        const v2f resid = vfma(R.C0v, X0, vfma(R.C1v, X1, vfma(R.CB2, XC, R.NCBv)));
        const v2f l = vmax0(zCS + resid);
        zCS = vfma(Bv, l - lpCS, l);
        lnCS = l;
    }
}

// ---- FISTA mutable state per problem ----
struct Fst {
    v2f LAE[3], LAO[3], ZV[3];
    v2f laCSE, laCSO, zCS;
};

__global__ __launch_bounds__(256, 1) void cbf_fista12(
    const float* __restrict__ u_nom,    // (B,2)
    const float* __restrict__ v_cur,    // (B,1)
    const float* __restrict__ p_obs,    // (B,10,2)
    const float* __restrict__ obs_mask, // (B,10)
    const float* __restrict__ p_ag,     // (B,7,2)
    const float* __restrict__ v_ag,     // (B,7,2)
    const float* __restrict__ ag_mask,  // (B,7)
    const float* __restrict__ p_c,      // (B,1,2)
    const float* __restrict__ v_c,      // (B,1,2)
    const float* __restrict__ c_mask,   // (B,1)
    float* __restrict__ out,            // (B,2)
    int B)
{
    const int t = blockIdx.x * 256 + threadIdx.x;
    const int q = t >> 2;        // quad index = problem-pair index
    const int sub = t & 3;
    const int half = (B + 1) >> 1;
    if (q >= half) return;       // whole quads exit together (q uniform in quad)

    const int pa = q;
    const int pbi = q + half;
    const bool hasB = (pbi < B);
    const int pb = hasB ? pbi : pa;   // clamp: redundant work, store suppressed

    Rows Ra, Rb;
    build_rows(pa, sub, u_nom, v_cur, p_obs, obs_mask, p_ag, v_ag, ag_mask, p_c, v_c, c_mask, Ra);
    build_rows(pb, sub, u_nom, v_cur, p_obs, obs_mask, p_ag, v_ag, ag_mask, p_c, v_c, c_mask, Rb);

    // ---- Power iteration, both problems in ONE loop (chains interleave) ----
    v2f PVa[3], PVb[3];
#pragma unroll
    for (int k = 0; k < 3; ++k) { PVa[k] = v2f{1.f, 1.f}; PVb[k] = v2f{1.f, 1.f}; }
    float pvCa = 1.f, pvSa = 1.f, pvCb = 1.f, pvSb = 1.f;

#pragma unroll 1
    for (int o = 0; o < N_POWER / 2; ++o) {
        apply_M(Ra, PVa, pvCa, pvSa);
        apply_M(Rb, PVb, pvCb, pvSb);
        apply_M(Ra, PVa, pvCa, pvSa);
        apply_M(Rb, PVb, pvCb, pvSb);
        pnorm(PVa, pvCa, pvSa);
        pnorm(PVb, pvCb, pvSb);
    }
    float nsha, pAa, nshb, pAb;
    step_consts(Ra, PVa, pvCa, pvSa, nsha, pAa);
    step_consts(Rb, PVb, pvCb, pvSb, nshb, pAb);

    // Fold pA = -step*PINV_S into the matvec-side slack coefficients once.
    v2f RA2a[3], RA2b[3];
#pragma unroll
    for (int k = 0; k < 3; ++k) {
        RA2a[k] = Ra.RA[k] * v2f{pAa, pAa};
        RA2b[k] = Rb.RA[k] * v2f{pAb, pAb};
    }
    const v2f CB2sa = Ra.CB2 * v2f{pAa, pAa};   // {pA*cB, -pA}
    const v2f CB2sb = Rb.CB2 * v2f{pAb, pAb};

    // ---- FISTA, both problems in ONE loop ----
    Fst Sa, Sb;
#pragma unroll
    for (int k = 0; k < 3; ++k) {
        Sa.LAE[k] = v2f{0.f, 0.f}; Sa.LAO[k] = v2f{0.f, 0.f}; Sa.ZV[k] = v2f{0.f, 0.f};
        Sb.LAE[k] = v2f{0.f, 0.f}; Sb.LAO[k] = v2f{0.f, 0.f}; Sb.ZV[k] = v2f{0.f, 0.f};
    }
    Sa.laCSE = v2f{0.f, 0.f}; Sa.laCSO = v2f{0.f, 0.f}; Sa.zCS = v2f{0.f, 0.f};
    Sb.laCSE = v2f{0.f, 0.f}; Sb.laCSO = v2f{0.f, 0.f}; Sb.zCS = v2f{0.f, 0.f};

    BOct bo = BETA8.q[0];
#pragma unroll 1
    for (int o = 0; o < N_FISTA / 4; ++o) {
        const BOct bn = BETA8.q[o + 1];   // prefetch next oct (pad entry at end)
        const v2f B0 = {bo.b[0], bo.b[1]};
        const v2f B1 = {bo.b[2], bo.b[3]};
        const v2f B2 = {bo.b[4], bo.b[5]};
        const v2f B3 = {bo.b[6], bo.b[7]};
        // it=4o   (writes E)
        half_step(Ra, RA2a, CB2sa, nsha, Sa.ZV, Sa.zCS, Sa.LAE, Sa.LAO, Sa.laCSE, Sa.laCSO, B0);
        half_step(Rb, RA2b, CB2sb, nshb, Sb.ZV, Sb.zCS, Sb.LAE, Sb.LAO, Sb.laCSE, Sb.laCSO, B0);
        // it=4o+1 (writes O)
        half_step(Ra, RA2a, CB2sa, nsha, Sa.ZV, Sa.zCS, Sa.LAO, Sa.LAE, Sa.laCSO, Sa.laCSE, B1);
        half_step(Rb, RA2b, CB2sb, nshb, Sb.ZV, Sb.zCS, Sb.LAO, Sb.LAE, Sb.laCSO, Sb.laCSE, B1);
        // it=4o+2 (writes E)
        half_step(Ra, RA2a, CB2sa, nsha, Sa.ZV, Sa.zCS, Sa.LAE, Sa.LAO, Sa.laCSE, Sa.laCSO, B2);
        half_step(Rb, RA2b, CB2sb, nshb, Sb.ZV, Sb.zCS, Sb.LAE, Sb.LAO, Sb.laCSE, Sb.laCSO, B2);
        // it=4o+3 (writes O)
        half_step(Ra, RA2a, CB2sa, nsha, Sa.ZV, Sa.zCS, Sa.LAO, Sa.LAE, Sa.laCSO, Sa.laCSE, B3);
        half_step(Rb, RA2b, CB2sb, nshb, Sb.ZV, Sb.zCS, Sb.LAO, Sb.LAE, Sb.laCSO, Sb.laCSE, B3);
        bo = bn;
    }

    // ---- Final primal (last write was LAO / laCSO) ----
    {
        v2f A0 = vfma(Ra.R0[0], Sa.LAO[0], vfma(Ra.R0[1], Sa.LAO[1], Ra.R0[2] * Sa.LAO[2]));
        v2f A1 = vfma(Ra.R1[0], Sa.LAO[0], vfma(Ra.R1[1], Sa.LAO[1], Ra.R1[2] * Sa.LAO[2]));
        float a0 = A0.x + A0.y, a1 = A1.x + A1.y;
        a0 = dpp_xor_add<0xB1>(a0); a0 = dpp_xor_add<0x4E>(a0);
        a1 = dpp_xor_add<0xB1>(a1); a1 = dpp_xor_add<0x4E>(a1);
        a0 = fmaf(Ra.c0, Sa.laCSO.x, a0);
        a1 = fmaf(Ra.c1, Sa.laCSO.x, a1);
        if (sub == 0) {
            out[2 * pa]     = fmaf(nsha, a0, Ra.u0);
            out[2 * pa + 1] = fmaf(nsha, a1, Ra.u1);
        }
    }
    {
        v2f A0 = vfma(Rb.R0[0], Sb.LAO[0], vfma(Rb.R0[1], Sb.LAO[1], Rb.R0[2] * Sb.LAO[2]));
        v2f A1 = vfma(Rb.R1[0], Sb.LAO[0], vfma(Rb.R1[1], Sb.LAO[1], Rb.R1[2] * Sb.LAO[2]));
        float a0 = A0.x + A0.y, a1 = A1.x + A1.y;
        a0 = dpp_xor_add<0xB1>(a0); a0 = dpp_xor_add<0x4E>(a0);
        a1 = dpp_xor_add<0xB1>(a1); a1 = dpp_xor_add<0x4E>(a1);
        a0 = fmaf(Rb.c0, Sb.laCSO.x, a0);
        a1 = fmaf(Rb.c1, Sb.laCSO.x, a1);
        if (sub == 0 && hasB) {
            out[2 * pbi]     = fmaf(nshb, a0, Rb.u0);
            out[2 * pbi + 1] = fmaf(nshb, a1, Rb.u1);
        }
    }
}

extern "C" void kernel_launch(void* const* d_in, const int* in_sizes, int n_in,
                              void* d_out, int out_size, void* d_ws, size_t ws_size,
                              hipStream_t stream) {
    const float* u_nom    = (const float*)d_in[0];
    const float* v_cur    = (const float*)d_in[1];
    const float* p_obs    = (const float*)d_in[2];
    const float* obs_mask = (const float*)d_in[3];
    const float* p_ag     = (const float*)d_in[4];
    const float* v_ag     = (const float*)d_in[5];
    const float* ag_mask  = (const float*)d_in[6];
    const float* p_c      = (const float*)d_in[7];
    const float* v_c      = (const float*)d_in[8];
    const float* c_mask   = (const float*)d_in[9];
    float* out = (float*)d_out;

    const int B = in_sizes[0] / 2;
    const int half = (B + 1) / 2;
    const long long threads = 4LL * half;
    const int grid = (int)((threads + 255) / 256);
    cbf_fista12<<<grid, 256, 0, stream>>>(
        u_nom, v_cur, p_obs, obs_mask, p_ag, v_ag, ag_mask, p_c, v_c, c_mask, out, B);
}

// Round 4
// 144.081 us; speedup vs baseline: 1.1303x; 1.1303x over previous
//
#include <hip/hip_runtime.h>

// Batched CBF-QP dual FISTA — r13: problem-PAIR packed fp32.
// r12 post-mortem: busy-cycle product identical to r11 (62 µs-equiv) but wall
// time +19% -> the scheduler re-serialized the two hand-interleaved chains to
// minimize register pressure (VGPR=72, not ~140). Fix: make ILP structural.
// Each thread owns TWO problems (A at q, B at q+half); every v2f holds
// {A_value, B_value}, so every v_pk_fma_f32 advances both dependency chains
// in lockstep — the scheduler cannot serialize them.
//   - 4 lanes/quad per problem-pair, same 25-row partition per problem:
//     lane0 obs0..5; lane1 obs6..9,slack0,box_a-; lane2 nei0..5;
//     lane3 nei6,slack1,box_a+,box_w-,box_w+,pad. conn+slack2 replicated.
//   - 6 row slots/lane/problem stored as 6 v2f {A_k,B_k}; the 6-slot dot
//     product accumulates inside the packed fma tree (depth 4), so no
//     scalar pair-adds; X0={x0A,x0B} feeds residual fmas directly (no splat).
//   - 65536 threads = 1024 waves = 1 wave/SIMD; ILP-2 baked into each instr.
// Sustained-clock note: fp32-VALU-saturated kernels run ~1.6 GHz on MI355X.

typedef float v2f __attribute__((ext_vector_type(2)));

namespace {
constexpr int N_POWER = 30;   // even
constexpr int N_FISTA = 300;  // divisible by 4
constexpr float PINV_S = 1.0f / 200.0f;  // 1/(2*W_SLACK)
constexpr float BIG = 1000.0f;

constexpr double csqrt(double x) {
    double r = x * 0.5 + 0.5;
    for (int i = 0; i < 50; ++i) r = 0.5 * (r + x / r);
    return r;
}
// beta pre-duplicated {b,b} (same beta for both packed problems at a given
// iteration); one scalar 32B load per 4 iterations, prefetched one ahead.
struct alignas(32) BOct { float b[8]; };
struct BetaTab8 { BOct q[N_FISTA / 4 + 1]; };  // +1 pad oct for prefetch
constexpr BetaTab8 make_beta8() {
    BetaTab8 t{};
    float tk = 1.0f;
    for (int k = 0; k < N_FISTA; ++k) {
        const float tk1 = 0.5f * (1.0f + (float)csqrt(1.0 + 4.0 * (double)tk * (double)tk));
        const float bb = (tk - 1.0f) / tk1;
        t.q[k / 4].b[(k % 4) * 2]     = bb;
        t.q[k / 4].b[(k % 4) * 2 + 1] = bb;
        tk = tk1;
    }
    return t;
}
}
__constant__ BetaTab8 BETA8 = make_beta8();

template <int CTRL>
__device__ __forceinline__ float dpp_xor_add(float x) {
    // CTRL: 0xB1 = quad_perm(1,0,3,2) = xor1 ; 0x4E = quad_perm(2,3,0,1) = xor2
    // mov_dpp + add: compiler handles DPP read-after-VALU hazards and fuses
    // via GCNDPPCombine (r10 lesson: raw asm v_add_f32_dpp skips hazard nops).
    int perm = __builtin_amdgcn_mov_dpp(__float_as_int(x), CTRL, 0xF, 0xF, true);
    return x + __int_as_float(perm);
}
__device__ __forceinline__ float dpp2(float x) {   // full quad sum
    return dpp_xor_add<0x4E>(dpp_xor_add<0xB1>(x));
}

__device__ __forceinline__ v2f vfma(v2f a, v2f b, v2f c) {
    return __builtin_elementwise_fma(a, b, c);
}
__device__ __forceinline__ v2f vmax0(v2f a) {
    const v2f z = {0.f, 0.f};
    return __builtin_elementwise_max(a, z);
}
// 6-slot packed dot product, tree-split: depth 4, two independent halves.
__device__ __forceinline__ v2f tree6(const v2f (&C)[6], const v2f (&Z)[6]) {
    v2f s0 = vfma(C[1], Z[1], C[0] * Z[0]);
    s0 = vfma(C[2], Z[2], s0);
    v2f s1 = vfma(C[4], Z[4], C[3] * Z[3]);
    s1 = vfma(C[5], Z[5], s1);
    return s0 + s1;
}

struct ConnS { float c0, c1, cB, ncb, u0, u1; };

__device__ __forceinline__ void build_scalar(
    int p, int sub,
    const float* __restrict__ u_nom, const float* __restrict__ v_cur,
    const float* __restrict__ p_obs, const float* __restrict__ obs_mask,
    const float* __restrict__ p_ag,  const float* __restrict__ v_ag,
    const float* __restrict__ ag_mask, const float* __restrict__ p_c,
    const float* __restrict__ v_c,   const float* __restrict__ c_mask,
    float (&r0)[6], float (&r1)[6], float (&rA)[6], float (&nb)[6], ConnS& cs)
{
    const float v = v_cur[p];
    cs.u0 = u_nom[2 * p];
    cs.u1 = u_nom[2 * p + 1];

#pragma unroll
    for (int s = 0; s < 6; ++s) { r0[s] = 0.f; r1[s] = 0.f; rA[s] = 0.f; nb[s] = -BIG; }

    auto obs_row = [&](int i, int s) {
        const float lx = p_obs[(p * 10 + i) * 2];
        const float ly = p_obs[(p * 10 + i) * 2 + 1];
        const float m  = obs_mask[p * 10 + i];
        const float h   = lx * lx + ly * ly - 0.25f;            // D_OBS^2
        const float hd  = -2.f * lx * v;
        const float rhs = 2.f * v * v + 3.f * hd + 2.f * h;     // DAMP=3, STIFF=2
        r0[s] = 2.f * lx * m;
        r1[s] = 2.f * ly * v * m;
        rA[s] = -m;
        nb[s] = (m > 0.f) ? -rhs : -BIG;
    };
    auto nei_row = [&](int j, int s) {
        const float ax  = p_ag[(p * 7 + j) * 2];
        const float ay  = p_ag[(p * 7 + j) * 2 + 1];
        const float vjx = v_ag[(p * 7 + j) * 2];
        const float vjy = v_ag[(p * 7 + j) * 2 + 1];
        const float m   = ag_mask[p * 7 + j];
        const float h   = ax * ax + ay * ay - 0.64f;            // D_SAFE^2
        const float hd  = -2.f * ax * v + 2.f * (ax * vjx + ay * vjy);
        const float hdd = 2.f * v * v - 2.f * v * vjx
                        + 2.f * (-v * vjx + vjx * vjx + vjy * vjy);
        const float rhs = hdd + 3.f * hd + 2.f * h;             // DAMP_A=3, STIFF_A=2
        r0[s] = 2.f * ax * m;
        r1[s] = (2.f * ay * v - 2.f * ay * vjx + 2.f * ax * vjy) * m;
        rA[s] = -m;
        nb[s] = (m > 0.f) ? -rhs : -BIG;
    };

    if (sub == 0) {
        obs_row(0, 0); obs_row(1, 1); obs_row(2, 2);
        obs_row(3, 3); obs_row(4, 4); obs_row(5, 5);
    } else if (sub == 1) {
        obs_row(6, 0); obs_row(7, 1); obs_row(8, 2); obs_row(9, 3);
        rA[4] = -1.f; nb[4] = 0.f;     // slack0: -delta_obs <= 0 (col2)
        r0[5] = -1.f; nb[5] = -2.f;    // -a <= A_MAX
    } else if (sub == 2) {
        nei_row(0, 0); nei_row(1, 1); nei_row(2, 2);
        nei_row(3, 3); nei_row(4, 4); nei_row(5, 5);
    } else {
        nei_row(6, 0);
        rA[1] = -1.f; nb[1] = 0.f;     // slack1: -delta_agent <= 0 (col3)
        r0[2] =  1.f; nb[2] = -2.f;    //  a <= A_MAX
        r1[3] = -1.f; nb[3] = -1.f;    // -w <= W_MAX
        r1[4] =  1.f; nb[4] = -1.f;    //  w <= W_MAX
        // slot5 = pad (zero coeffs, nb=-BIG): lambda provably stays 0
    }

    // conn + slack2 (col4), replicated in every lane
    {
        const float cx  = p_c[2 * p];
        const float cy  = p_c[2 * p + 1];
        const float cvx = v_c[2 * p];
        const float cvy = v_c[2 * p + 1];
        const float m   = c_mask[p];
        const float h   = 25.f - (cx * cx + cy * cy);           // D_MAX^2
        const float hd  = 2.f * cx * v - 2.f * (cx * cvx + cy * cvy);
        const float hdd = -(2.f * v * v - 2.f * v * cvx
                          + 2.f * (-v * cvx + cvx * cvx + cvy * cvy));
        const float rhs = hdd + 3.f * hd + 2.f * h;             // DAMP_CN=3, STIFF_CN=2
        cs.c0 = -2.f * cx * m;
        cs.c1 = -(2.f * cy * v - 2.f * cy * cvx + 2.f * cx * cvy) * m;
        cs.cB = -m;
        cs.ncb = (m > 0.f) ? -rhs : -BIG;
    }
}

__global__ __launch_bounds__(256, 1) void cbf_fista13(
    const float* __restrict__ u_nom,    // (B,2)
    const float* __restrict__ v_cur,    // (B,1)
    const float* __restrict__ p_obs,    // (B,10,2)
    const float* __restrict__ obs_mask, // (B,10)
    const float* __restrict__ p_ag,     // (B,7,2)
    const float* __restrict__ v_ag,     // (B,7,2)
    const float* __restrict__ ag_mask,  // (B,7)
    const float* __restrict__ p_c,      // (B,1,2)
    const float* __restrict__ v_c,      // (B,1,2)
    const float* __restrict__ c_mask,   // (B,1)
    float* __restrict__ out,            // (B,2)
    int B)
{
    const int t = blockIdx.x * 256 + threadIdx.x;
    const int q = t >> 2;        // quad index = problem-pair index
    const int sub = t & 3;
    const int half = (B + 1) >> 1;
    if (q >= half) return;       // whole quads exit together

    const int pa = q;
    const int pbi = q + half;
    const bool hasB = (pbi < B);
    const int pb = hasB ? pbi : pa;   // clamp: redundant work, store suppressed

    float r0a[6], r1a[6], rAa[6], nba[6]; ConnS ca;
    float r0b[6], r1b[6], rAb[6], nbb[6]; ConnS cb;
    build_scalar(pa, sub, u_nom, v_cur, p_obs, obs_mask, p_ag, v_ag, ag_mask, p_c, v_c, c_mask,
                 r0a, r1a, rAa, nba, ca);
    build_scalar(pb, sub, u_nom, v_cur, p_obs, obs_mask, p_ag, v_ag, ag_mask, p_c, v_c, c_mask,
                 r0b, r1b, rAb, nbb, cb);

    // pack {A,B} per slot
    v2f R0[6], R1[6], RA[6], NB[6];
#pragma unroll
    for (int k = 0; k < 6; ++k) {
        R0[k] = v2f{r0a[k], r0b[k]};
        R1[k] = v2f{r1a[k], r1b[k]};
        RA[k] = v2f{rAa[k], rAb[k]};
        NB[k] = v2f{nba[k], nbb[k]};
    }
    const v2f c0p  = {ca.c0,  cb.c0};
    const v2f c1p  = {ca.c1,  cb.c1};
    const v2f cBp  = {ca.cB,  cb.cB};
    const v2f ncbp = {ca.ncb, cb.ncb};
    const v2f u0p  = {ca.u0,  cb.u0};
    const v2f u1p  = {ca.u1,  cb.u1};

    // ---- Power iteration: L = lambda_max(A Pinv A^T), normalize every 2nd ----
    v2f PV[6];
#pragma unroll
    for (int k = 0; k < 6; ++k) PV[k] = v2f{1.f, 1.f};
    v2f pvC = {1.f, 1.f}, pvS = {1.f, 1.f};

    auto apply_M = [&]() {
        const v2f A0 = tree6(R0, PV);
        const v2f A1 = tree6(R1, PV);
        const v2f AA = tree6(RA, PV);
        const float a0A = dpp2(A0.x), a0B = dpp2(A0.y);
        const float a1A = dpp2(A1.x), a1B = dpp2(A1.y);
        const float aAA = dpp_xor_add<0xB1>(AA.x);
        const float aAB = dpp_xor_add<0xB1>(AA.y);
        const v2f a0p = vfma(c0p, pvC, v2f{a0A, a0B});
        const v2f a1p = vfma(c1p, pvC, v2f{a1A, a1B});
        const v2f aCp = vfma(cBp, pvC, -pvS);
        const v2f x0 = a0p * 0.5f, x1 = a1p * 0.5f;
        const v2f xA = v2f{aAA, aAB} * PINV_S;
        const v2f xC = aCp * PINV_S;
#pragma unroll
        for (int k = 0; k < 6; ++k)
            PV[k] = vfma(R0[k], x0, vfma(R1[k], x1, RA[k] * xA));
        pvC = vfma(c0p, x0, vfma(c1p, x1, cBp * xC));
        pvS = -xC;
    };

#pragma unroll 1
    for (int o = 0; o < N_POWER / 2; ++o) {
        apply_M();
        apply_M();
        const v2f NS = tree6(PV, PV);
        const float nA = dpp2(NS.x), nB = dpp2(NS.y);
        const v2f nsq = vfma(pvC, pvC, vfma(pvS, pvS, v2f{nA, nB}));
        const float invA = __builtin_amdgcn_rsqf(nsq.x + 1e-24f);
        const float invB = __builtin_amdgcn_rsqf(nsq.y + 1e-24f);
        const v2f INV = {invA, invB};
#pragma unroll
        for (int k = 0; k < 6; ++k) PV[k] = PV[k] * INV;
        pvC = pvC * INV;
        pvS = pvS * INV;
    }

    v2f nsh_p, pA_p;   // {-step/2}, {-step*PINV_S} per problem
    {
        const v2f A0 = tree6(R0, PV);
        const v2f A1 = tree6(R1, PV);
        const v2f AA = tree6(RA, PV);
        const float a0A = dpp2(A0.x), a0B = dpp2(A0.y);
        const float a1A = dpp2(A1.x), a1B = dpp2(A1.y);
        const float aAA = dpp_xor_add<0xB1>(AA.x);
        const float aAB = dpp_xor_add<0xB1>(AA.y);
        const v2f a0p = vfma(c0p, pvC, v2f{a0A, a0B});
        const v2f a1p = vfma(c1p, pvC, v2f{a1A, a1B});
        const v2f aCp = vfma(cBp, pvC, -pvS);
        // pair sums of slack cols: after xor1, lanes {0,1} hold col2, {2,3} col3
        const v2f aAp = {aAA, aAB};
        const v2f sq = aAp * aAp;
        const float tqA = dpp_xor_add<0x4E>(sq.x);   // col2^2 + col3^2, problem A
        const float tqB = dpp_xor_add<0x4E>(sq.y);
        const v2f tq = vfma(aCp, aCp, v2f{tqA, tqB});
        const v2f hterm = vfma(a0p, a0p, a1p * a1p) * 0.5f;
        const v2f L = vfma(tq, v2f{PINV_S, PINV_S}, hterm);
        const float stA = __builtin_amdgcn_rcpf(L.x + 1e-6f);
        const float stB = __builtin_amdgcn_rcpf(L.y + 1e-6f);
        nsh_p = v2f{stA, stB} * -0.5f;
        pA_p  = v2f{stA, stB} * -PINV_S;
    }

    // Fold pA = -step*PINV_S into the matvec-side slack coefficients once.
    v2f RA2[6];
#pragma unroll
    for (int k = 0; k < 6; ++k) RA2[k] = RA[k] * pA_p;
    const v2f cBs = cBp * pA_p;
    const v2f npA = -pA_p;

    // ---- FISTA on the dual, z = y/step scale, lambda ping-pong ----
    v2f ZV[6], LAE[6], LAO[6];
#pragma unroll
    for (int k = 0; k < 6; ++k) {
        ZV[k] = v2f{0.f, 0.f}; LAE[k] = v2f{0.f, 0.f}; LAO[k] = v2f{0.f, 0.f};
    }
    v2f zC = {0.f, 0.f}, zS = {0.f, 0.f};
    v2f lCE = {0.f, 0.f}, lCO = {0.f, 0.f}, lSE = {0.f, 0.f}, lSO = {0.f, 0.f};

    auto half_step = [&](v2f (&ln)[6], const v2f (&lp)[6],
                         v2f& lnC, v2f lpC, v2f& lnS, v2f lpS, v2f Bv) {
        const v2f A0 = tree6(R0, ZV);
        const v2f A1 = tree6(R1, ZV);
        const v2f AA = tree6(RA2, ZV);
        const float a0A = dpp2(A0.x), a0B = dpp2(A0.y);
        const float a1A = dpp2(A1.x), a1B = dpp2(A1.y);
        const float xAA = dpp_xor_add<0xB1>(AA.x);   // == xA (pA pre-folded)
        const float xAB = dpp_xor_add<0xB1>(AA.y);
        const v2f XA = {xAA, xAB};
        const v2f xC = vfma(cBs, zC, npA * zS);      // pA*(cB*zC - zS)
        const v2f X0 = vfma(nsh_p, vfma(c0p, zC, v2f{a0A, a0B}), u0p);
        const v2f X1 = vfma(nsh_p, vfma(c1p, zC, v2f{a1A, a1B}), u1p);
#pragma unroll
        for (int k = 0; k < 6; ++k) {
            const v2f resid = vfma(R0[k], X0, vfma(R1[k], X1, vfma(RA[k], XA, NB[k])));
            const v2f l = vmax0(ZV[k] + resid);
            ZV[k] = vfma(Bv, l - lp[k], l);
            ln[k] = l;
        }
        {   // conn row, both problems packed
            const v2f residC = vfma(c0p, X0, vfma(c1p, X1, vfma(cBp, xC, ncbp)));
            const v2f l = vmax0(zC + residC);
            zC = vfma(Bv, l - lpC, l);
            lnC = l;
        }
        {   // slack2 row: resid = -xC
            const v2f l = vmax0(zS - xC);
            zS = vfma(Bv, l - lpS, l);
            lnS = l;
        }
    };

    BOct bo = BETA8.q[0];
#pragma unroll 1
    for (int o = 0; o < N_FISTA / 4; ++o) {
        const BOct bn = BETA8.q[o + 1];   // prefetch next oct (pad entry at end)
        half_step(LAE, LAO, lCE, lCO, lSE, lSO, v2f{bo.b[0], bo.b[1]});  // it=4o
        half_step(LAO, LAE, lCO, lCE, lSO, lSE, v2f{bo.b[2], bo.b[3]});  // it=4o+1
        half_step(LAE, LAO, lCE, lCO, lSE, lSO, v2f{bo.b[4], bo.b[5]});  // it=4o+2
        half_step(LAO, LAE, lCO, lCE, lSO, lSE, v2f{bo.b[6], bo.b[7]});  // it=4o+3
        bo = bn;
    }

    // ---- Final primal from lambda = step*Lambda (last write was LAO / lCO) ----
    {
        const v2f A0 = tree6(R0, LAO);
        const v2f A1 = tree6(R1, LAO);
        const float a0A = dpp2(A0.x), a0B = dpp2(A0.y);
        const float a1A = dpp2(A1.x), a1B = dpp2(A1.y);
        const v2f a0p = vfma(c0p, lCO, v2f{a0A, a0B});
        const v2f a1p = vfma(c1p, lCO, v2f{a1A, a1B});
        const v2f o0 = vfma(nsh_p, a0p, u0p);
        const v2f o1 = vfma(nsh_p, a1p, u1p);
        if (sub == 0) {
            out[2 * pa]     = o0.x;
            out[2 * pa + 1] = o1.x;
            if (hasB) {
                out[2 * pbi]     = o0.y;
                out[2 * pbi + 1] = o1.y;
            }
        }
    }
}

extern "C" void kernel_launch(void* const* d_in, const int* in_sizes, int n_in,
                              void* d_out, int out_size, void* d_ws, size_t ws_size,
                              hipStream_t stream) {
    const float* u_nom    = (const float*)d_in[0];
    const float* v_cur    = (const float*)d_in[1];
    const float* p_obs    = (const float*)d_in[2];
    const float* obs_mask = (const float*)d_in[3];
    const float* p_ag     = (const float*)d_in[4];
    const float* v_ag     = (const float*)d_in[5];
    const float* ag_mask  = (const float*)d_in[6];
    const float* p_c      = (const float*)d_in[7];
    const float* v_c      = (const float*)d_in[8];
    const float* c_mask   = (const float*)d_in[9];
    float* out = (float*)d_out;

    const int B = in_sizes[0] / 2;
    const int half = (B + 1) / 2;
    const long long threads = 4LL * half;
    const int grid = (int)((threads + 255) / 256);
    cbf_fista13<<<grid, 256, 0, stream>>>(
        u_nom, v_cur, p_obs, obs_mask, p_ag, v_ag, ag_mask, p_c, v_c, c_mask, out, B);
}